// Round 1
// baseline (392.314 us; speedup 1.0000x reference)
//
#include <hip/hip_runtime.h>

typedef _Float16 f16;
typedef _Float16 f16x4 __attribute__((ext_vector_type(4)));
typedef _Float16 f16x8 __attribute__((ext_vector_type(8)));
typedef float    f32x4 __attribute__((ext_vector_type(4)));

#define S2C 2.88539008177792681472f   // 2*log2(e)

// ws layout, f16-element offsets (unchanged — prep is identical to previous round)
#define OFF_STF  0u          // states A-frags [10][256 rg2][2 rt][2 ks][64 lane][8]  5242880
#define OFF_AC   5242880u    // action f16 compact [8192][10][16]                     1310720
#define OFF_WEF  6553600u    // W_edge B-frags [90][4 ks][8 cg][64 lane][8]           1474560
#define OFF_WNF  8028160u    // W_node B-frags K-permuted [10][7 ks][4 c][64 lane][8]  143360
#define OFF_BE2  8171520u    // f32: be2[11520], bn2[640]; then 8 f16 zeros
#define OFF_Z    8195840u    // 8 f16 zeros (pad source for action kstep)

__device__ __forceinline__ float fast_exp2(float x){
#if __has_builtin(__builtin_amdgcn_exp2f)
    return __builtin_amdgcn_exp2f(x);
#else
    return exp2f(x);
#endif
}
__device__ __forceinline__ float fast_rcp(float x){
#if __has_builtin(__builtin_amdgcn_rcpf)
    return __builtin_amdgcn_rcpf(x);
#else
    return 1.0f/x;
#endif
}

#define MFMA16(a,b,c) __builtin_amdgcn_mfma_f32_16x16x32_f16(a,b,c,0,0,0)

// ---------------- prologue: cvt + fragment-order + bias scale (unchanged) ----------------
__global__ void prep(const float* __restrict__ st, const float* __restrict__ ac,
                     const float* __restrict__ We, const float* __restrict__ be,
                     const float* __restrict__ Wn, const float* __restrict__ bn,
                     f16* __restrict__ ws16){
    const int bid = blockIdx.x, t = threadIdx.x;
    if (bid < 2560){                                   // states -> A-fragment order
        int g = bid*256 + t;                           // [node][rg2][rt][ks][lane]
        int lane = g&63, ks = (g>>6)&1, rt = (g>>7)&1, rg2 = (g>>8)&255, node = g>>16;
        int row = rg2*32 + rt*16 + (lane&15);
        int k   = ks*32 + (lane>>4)*8;
        const float* src = st + ((size_t)row*10 + node)*64 + k;
        const float4 v0 = *(const float4*)src;
        const float4 v1 = *(const float4*)(src+4);
        f16x8 h; h[0]=(f16)v0.x; h[1]=(f16)v0.y; h[2]=(f16)v0.z; h[3]=(f16)v0.w;
                 h[4]=(f16)v1.x; h[5]=(f16)v1.y; h[6]=(f16)v1.z; h[7]=(f16)v1.w;
        *(f16x8*)(ws16 + OFF_STF + (size_t)g*8) = h;
    } else if (bid < 3840){                            // action f32 -> f16 compact
        int g = (bid-2560)*256 + t;                    // 327680 float4s
        const float4 v = ((const float4*)ac)[g];
        f16x4 h; h[0]=(f16)v.x; h[1]=(f16)v.y; h[2]=(f16)v.z; h[3]=(f16)v.w;
        *(f16x4*)(ws16 + OFF_AC + (size_t)g*4) = h;
    } else if (bid < 4560){                            // W_edge -> B-fragment order
        int g = (bid-3840)*256 + t;                    // < 184320
        int l = g & 15, q = (g>>4)&3, cg = (g>>6)&7, ks = (g>>9)&3, e = g>>11;
        const float* src = We + e*16384 + (ks*32 + q*8)*128 + cg*16 + l;
        f16x8 h;
        #pragma unroll
        for (int u=0;u<8;u++) h[u] = (f16)src[u*128];
        *(f16x8*)(ws16 + OFF_WEF + (size_t)g*8) = h;
    } else if (bid < 4630){                            // W_node -> B-frags, K-permuted
        int g = (bid-4560)*256 + t;                    // < 17920
        if (g < 17920){
            int l = g&15, q=(g>>4)&3, c=(g>>6)&3, r=g>>8;
            int ks2 = r % 7, kn = r / 7;
            f16x8 h;
            #pragma unroll
            for (int u=0;u<8;u++){
                int knew = ks2*32 + q*8 + u;
                // K-order: [agg 0..127 -> f=knew+80][states/action 128..207 -> f=knew-128][pad]
                int f = (knew < 128) ? (knew + 80) : (knew - 128);
                h[u] = (knew < 208) ? (f16)Wn[kn*13312 + f*64 + c*16 + l] : (f16)0.0f;
            }
            *(f16x8*)(ws16 + OFF_WNF + (size_t)kn*14336 + ((size_t)(ks2*4+c)*64 + q*16 + l)*8) = h;
        }
    } else {                                           // biases * 2log2e, zero pad
        int g = (bid-4630)*256 + t;
        float* be2 = (float*)(ws16 + OFF_BE2);
        if (g < 11520)      be2[g] = S2C*be[g];
        else if (g < 12160) be2[g] = S2C*bn[g-11520];
        else if (g < 12168) ws16[OFF_Z + (g-12160)] = (f16)0.0f;
    }
}

// ---------------- main kernel: 128 rows/block, W_edge via double-buffered LDS ----------------
// 512-thread blocks (8 waves = 4 row-groups x 2 col-halves), 640 blocks.
// W_edge frags for edge e+1 are loaded global->reg at the TOP of edge-e body and
// ds_write'd into the alternate LDS buffer at the BOTTOM (latency hidden under the
// MFMA+tanh of edge e); the per-edge __syncthreads() provides the drain. All 8 waves
// read B-frags from LDS, so each 32 KB of W serves 128 rows instead of 32 (4x traffic cut).
// During edge 8 the same slot-staging pattern loads W_node frags into buffer 1;
// sAgg (128x128 f16 = 32 KB) unions into buffer 0 after stage 1.
__launch_bounds__(512, 4)
__global__ void gnn_main(const f16* __restrict__ ws16, float* __restrict__ out){
    __shared__ alignas(16) f16 sW[2][16384];           // 64 KB total -> 2 blocks/CU

    const f16* stf = ws16 + OFF_STF;
    const f16* Wef = ws16 + OFF_WEF;
    const float* be2 = (const float*)(ws16 + OFF_BE2);
    const float* bn2 = be2 + 11520;

    const int t = threadIdx.x, lane = t&63, wid = t>>6;   // wid 0..7
    const int l15 = lane&15, q = lane>>4, qo = q<<3;
    const int rg = wid>>1, cs = wid&1;                 // row-group 0..3, col-half 0..1

    // bijective XCD-chunk swizzle: 640 = 8 * 80; each XCD gets all-i x 8 rb values
    const int swz = (blockIdx.x & 7)*80 + (blockIdx.x >> 3);
    const int rb  = swz / 10;                          // 128-row group 0..63
    const int i   = swz - rb*10;                       // node 0..9
    const int e0  = 9*i;
    const int rbrow = rb*4 + rg;                       // this wave's 32-row chunk (0..255)

    // ---- prologue: stage edge-0 W into sW[0]; load ai + ajb[0] registers ----
    {
        const f16* wsrc = Wef + (size_t)e0*16384 + (size_t)(wid*4)*512 + (size_t)lane*8;
        f16x8 w0 = *(const f16x8*)(wsrc);
        f16x8 w1 = *(const f16x8*)(wsrc+512);
        f16x8 w2 = *(const f16x8*)(wsrc+1024);
        f16x8 w3 = *(const f16x8*)(wsrc+1536);
        f16* dst = &sW[0][wid*4*512 + lane*8];
        *(f16x8*)(dst)      = w0;
        *(f16x8*)(dst+512)  = w1;
        *(f16x8*)(dst+1024) = w2;
        *(f16x8*)(dst+1536) = w3;
    }
    f16x8 ai[4], ajb[2][4];
    {
        const f16* p = stf + ((size_t)i*256 + rbrow)*2048 + lane*8;
        ai[0] = *(const f16x8*)p;        ai[1] = *(const f16x8*)(p+512);
        ai[2] = *(const f16x8*)(p+1024); ai[3] = *(const f16x8*)(p+1536);
        const int j0 = (i==0) ? 1 : 0;
        const f16* pj = stf + ((size_t)j0*256 + rbrow)*2048 + lane*8;
        ajb[0][0] = *(const f16x8*)pj;        ajb[0][1] = *(const f16x8*)(pj+512);
        ajb[0][2] = *(const f16x8*)(pj+1024); ajb[0][3] = *(const f16x8*)(pj+1536);
    }
    __syncthreads();

    f32x4 agg[2][4] = {};

    #pragma unroll
    for (int e=0; e<9; ++e){
        const int cur = e&1, nxt = cur^1;
        const int ebase = e0 + e;

        // ---- issue staging loads for the NEXT buffer (W edge e+1, or W_node at e==8) ----
        f16x8 st0, st1, st2, st3;
        if (e < 8){
            const f16* wsrc = Wef + (size_t)(ebase+1)*16384 + (size_t)(wid*4)*512 + (size_t)lane*8;
            st0 = *(const f16x8*)(wsrc);
            st1 = *(const f16x8*)(wsrc+512);
            st2 = *(const f16x8*)(wsrc+1024);
            st3 = *(const f16x8*)(wsrc+1536);
        } else {
            const f16* wnf = ws16 + OFF_WNF + (size_t)i*14336 + wid*512 + lane*8;
            st0 = *(const f16x8*)(wnf);
            st1 = *(const f16x8*)(wnf + 8*512);
            st2 = *(const f16x8*)(wnf + 16*512);
            if (wid < 4) st3 = *(const f16x8*)(wnf + 24*512);
        }

        // ---- prefetch next edge's A-frags into alternate register buffer ----
        if (e < 8){
            const int j2 = (e+1) + ((e+1) >= i);
            const f16* pj = stf + ((size_t)j2*256 + rbrow)*2048 + lane*8;
            ajb[nxt][0] = *(const f16x8*)pj;
            ajb[nxt][1] = *(const f16x8*)(pj+512);
            ajb[nxt][2] = *(const f16x8*)(pj+1024);
            ajb[nxt][3] = *(const f16x8*)(pj+1536);
        }

        float bv[4];
        #pragma unroll
        for (int c=0; c<4; ++c) bv[c] = be2[ebase*128 + cs*64 + c*16 + l15];

        // ---- compute edge e from sW[cur] ----
        const f16* wb = &sW[cur][cs*4*512 + lane*8];
        #pragma unroll
        for (int rt=0; rt<2; ++rt){
            f32x4 msg[4] = {};
            #pragma unroll
            for (int ks4=0; ks4<4; ++ks4){
                f16x8 a = (ks4 < 2) ? ai[rt*2 + ks4] : ajb[cur][rt*2 + (ks4-2)];
                #pragma unroll
                for (int c=0; c<4; ++c){
                    f16x8 b = *(const f16x8*)(wb + (ks4*8 + c)*512);
                    msg[c] = MFMA16(a, b, msg[c]);
                }
            }
            // tanh + aggregate: sum tanh = 9 - 2*sum rcp(exp2(S2C*x+b2)+1)
            #pragma unroll
            for (int c=0; c<4; ++c)
                #pragma unroll
                for (int r2=0; r2<4; ++r2){
                    float tt = __builtin_fmaf(msg[c][r2], S2C, bv[c]);
                    float rr = fast_rcp(fast_exp2(tt) + 1.0f);
                    agg[rt][c][r2] = __builtin_fmaf(-2.0f, rr, agg[rt][c][r2]);
                }
        }

        // ---- write staged data into the alternate buffer (vmcnt wait lands here, hidden) ----
        if (e < 8){
            f16* dst = &sW[nxt][wid*4*512 + lane*8];
            *(f16x8*)(dst)      = st0;
            *(f16x8*)(dst+512)  = st1;
            *(f16x8*)(dst+1024) = st2;
            *(f16x8*)(dst+1536) = st3;
        } else {                                       // W_node frags -> sW[1]
            f16* dst = &sW[1][wid*512 + lane*8];
            *(f16x8*)(dst)        = st0;
            *(f16x8*)(dst+8*512)  = st1;
            *(f16x8*)(dst+16*512) = st2;
            if (wid < 4) *(f16x8*)(dst+24*512) = st3;
        }
        __syncthreads();
    }

    // ---- agg (C-layout) -> sAgg f16 in sW[0] (A-layout, swizzled), +9 fold ----
    {
        f16* sAgg = &sW[0][0];
        #pragma unroll
        for (int rt=0; rt<2; ++rt)
            #pragma unroll
            for (int c=0; c<4; ++c)
                #pragma unroll
                for (int r2=0; r2<4; ++r2){
                    int lrow = rg*32 + rt*16 + q*4 + r2;   // 0..127
                    int col  = cs*64 + c*16 + l15;         // 0..127
                    sAgg[lrow*128 + (((col>>3) ^ (lrow&7))<<3) + (col&7)] = (f16)(agg[rt][c][r2] + 9.0f);
                }
    }
    __syncthreads();

    // ---- stage 2: out = tanh([agg|states|action] @ Wn_perm[i] + bn) ; wave = 16 rows ----
    f32x4 acc[4] = {};
    const f16* acp = ws16 + OFF_AC;
    const f16* zb  = ws16 + OFF_Z;
    const int b0 = rb*128;
    #pragma unroll
    for (int ks2=0; ks2<7; ++ks2){
        f16x8 a;
        if (ks2 < 4){                                  // agg region (K 0..127) from LDS
            int lrow = wid*16 + l15;
            a = *(const f16x8*)(&sW[0][lrow*128 + (((ks2*4 + q) ^ (l15&7))<<3)]);
        } else if (ks2 < 6){                           // states region (K 128..191)
            a = *(const f16x8*)(stf + ((size_t)i*256 + rb*4 + (wid>>1))*2048
                                + (wid&1)*1024 + (ks2-4)*512 + lane*8);
        } else {                                       // action (K 192..207) + zero pad
            int row = b0 + wid*16 + l15;
            const f16* ap = (q < 2) ? (acp + ((size_t)row*10 + i)*16 + qo) : zb;
            a = *(const f16x8*)ap;
        }
        #pragma unroll
        for (int c=0; c<4; ++c){
            f16x8 bf = *(const f16x8*)(&sW[1][(ks2*4+c)*512 + lane*8]);
            acc[c] = MFMA16(a, bf, acc[c]);
        }
    }
    float bnv[4];
    #pragma unroll
    for (int c=0; c<4; ++c) bnv[c] = bn2[i*64 + c*16 + l15];
    #pragma unroll
    for (int c=0; c<4; ++c)
        #pragma unroll
        for (int r2=0; r2<4; ++r2){
            int row = b0 + wid*16 + q*4 + r2;
            int col = c*16 + l15;
            float tt = __builtin_fmaf(acc[c][r2], S2C, bnv[c]);
            float rr = fast_rcp(fast_exp2(tt) + 1.0f);
            out[((size_t)row*10 + i)*64 + col] = __builtin_fmaf(-2.0f, rr, 1.0f);
        }
}

extern "C" void kernel_launch(void* const* d_in, const int* in_sizes, int n_in,
                              void* d_out, int out_size, void* d_ws, size_t ws_size,
                              hipStream_t stream) {
    const float* states = (const float*)d_in[0];
    const float* action = (const float*)d_in[1];
    const float* W_edge = (const float*)d_in[2];
    const float* b_edge = (const float*)d_in[3];
    const float* W_node = (const float*)d_in[4];
    const float* b_node = (const float*)d_in[5];
    f16* ws16 = (f16*)d_ws;   // ~16.4 MB used

    hipLaunchKernelGGL(prep, dim3(4678), dim3(256), 0, stream,
                       states, action, W_edge, b_edge, W_node, b_node, ws16);
    hipLaunchKernelGGL(gnn_main, dim3(640), dim3(512), 0, stream,
                       ws16, (float*)d_out);
}

// Round 2
// 152.922 us; speedup vs baseline: 2.5654x; 2.5654x over previous
//
#include <hip/hip_runtime.h>

typedef _Float16 f16;
typedef _Float16 f16x4 __attribute__((ext_vector_type(4)));
typedef _Float16 f16x8 __attribute__((ext_vector_type(8)));
typedef float    f32x4 __attribute__((ext_vector_type(4)));

#define S2C 2.88539008177792681472f   // 2*log2(e)

// ws layout, f16-element offsets (unchanged — prep is identical to previous rounds)
#define OFF_STF  0u          // states A-frags [10][256 rg2][2 rt][2 ks][64 lane][8]  5242880
#define OFF_AC   5242880u    // action f16 compact [8192][10][16]                     1310720
#define OFF_WEF  6553600u    // W_edge B-frags [90][4 ks][8 cg][64 lane][8]           1474560
#define OFF_WNF  8028160u    // W_node B-frags K-permuted [10][7 ks][4 c][64 lane][8]  143360
#define OFF_BE2  8171520u    // f32: be2[11520], bn2[640]; then 8 f16 zeros
#define OFF_Z    8195840u    // 8 f16 zeros (pad source for action kstep)

__device__ __forceinline__ float fast_exp2(float x){
#if __has_builtin(__builtin_amdgcn_exp2f)
    return __builtin_amdgcn_exp2f(x);
#else
    return exp2f(x);
#endif
}
__device__ __forceinline__ float fast_rcp(float x){
#if __has_builtin(__builtin_amdgcn_rcpf)
    return __builtin_amdgcn_rcpf(x);
#else
    return 1.0f/x;
#endif
}

#define MFMA16(a,b,c) __builtin_amdgcn_mfma_f32_16x16x32_f16(a,b,c,0,0,0)

// ---------------- prologue: cvt + fragment-order + bias scale (unchanged) ----------------
__global__ void prep(const float* __restrict__ st, const float* __restrict__ ac,
                     const float* __restrict__ We, const float* __restrict__ be,
                     const float* __restrict__ Wn, const float* __restrict__ bn,
                     f16* __restrict__ ws16){
    const int bid = blockIdx.x, t = threadIdx.x;
    if (bid < 2560){                                   // states -> A-fragment order
        int g = bid*256 + t;                           // [node][rg2][rt][ks][lane]
        int lane = g&63, ks = (g>>6)&1, rt = (g>>7)&1, rg2 = (g>>8)&255, node = g>>16;
        int row = rg2*32 + rt*16 + (lane&15);
        int k   = ks*32 + (lane>>4)*8;
        const float* src = st + ((size_t)row*10 + node)*64 + k;
        const float4 v0 = *(const float4*)src;
        const float4 v1 = *(const float4*)(src+4);
        f16x8 h; h[0]=(f16)v0.x; h[1]=(f16)v0.y; h[2]=(f16)v0.z; h[3]=(f16)v0.w;
                 h[4]=(f16)v1.x; h[5]=(f16)v1.y; h[6]=(f16)v1.z; h[7]=(f16)v1.w;
        *(f16x8*)(ws16 + OFF_STF + (size_t)g*8) = h;
    } else if (bid < 3840){                            // action f32 -> f16 compact
        int g = (bid-2560)*256 + t;                    // 327680 float4s
        const float4 v = ((const float4*)ac)[g];
        f16x4 h; h[0]=(f16)v.x; h[1]=(f16)v.y; h[2]=(f16)v.z; h[3]=(f16)v.w;
        *(f16x4*)(ws16 + OFF_AC + (size_t)g*4) = h;
    } else if (bid < 4560){                            // W_edge -> B-fragment order
        int g = (bid-3840)*256 + t;                    // < 184320
        int l = g & 15, q = (g>>4)&3, cg = (g>>6)&7, ks = (g>>9)&3, e = g>>11;
        const float* src = We + e*16384 + (ks*32 + q*8)*128 + cg*16 + l;
        f16x8 h;
        #pragma unroll
        for (int u=0;u<8;u++) h[u] = (f16)src[u*128];
        *(f16x8*)(ws16 + OFF_WEF + (size_t)g*8) = h;
    } else if (bid < 4630){                            // W_node -> B-frags, K-permuted
        int g = (bid-4560)*256 + t;                    // < 17920
        if (g < 17920){
            int l = g&15, q=(g>>4)&3, c=(g>>6)&3, r=g>>8;
            int ks2 = r % 7, kn = r / 7;
            f16x8 h;
            #pragma unroll
            for (int u=0;u<8;u++){
                int knew = ks2*32 + q*8 + u;
                // K-order: [agg 0..127 -> f=knew+80][states/action 128..207 -> f=knew-128][pad]
                int f = (knew < 128) ? (knew + 80) : (knew - 128);
                h[u] = (knew < 208) ? (f16)Wn[kn*13312 + f*64 + c*16 + l] : (f16)0.0f;
            }
            *(f16x8*)(ws16 + OFF_WNF + (size_t)kn*14336 + ((size_t)(ks2*4+c)*64 + q*16 + l)*8) = h;
        }
    } else {                                           // biases * 2log2e, zero pad
        int g = (bid-4630)*256 + t;
        float* be2 = (float*)(ws16 + OFF_BE2);
        if (g < 11520)      be2[g] = S2C*be[g];
        else if (g < 12160) be2[g] = S2C*bn[g-11520];
        else if (g < 12168) ws16[OFF_Z + (g-12160)] = (f16)0.0f;
    }
}

// ---------------- main kernel: 128 rows/block, W via pointer-swapped LDS double buffer ----
// 512-thread blocks (8 waves = 4 row-groups x 2 col-halves), 640 blocks, 64 KB LDS
// -> 2 blocks/CU, 4 waves/SIMD.  Edge loop stays ROLLED (#pragma unroll 1): all register
// arrays are static-indexed (no scratch demotion — round-1 lesson), LDS double buffering
// is done by swapping addrspace(3) pointers.  Per edge: issue next-W global loads (vmcnt
// consumer is the ds_write at the bottom, hidden under MFMA+tanh), load this edge's
// A-frags, compute from sWc, write staged W to sWn, one barrier, swap.
__launch_bounds__(512, 4)
__global__ void gnn_main(const f16* __restrict__ ws16, float* __restrict__ out){
    __shared__ alignas(16) f16 sW0[16384];             // 32 KB
    __shared__ alignas(16) f16 sW1[16384];             // 32 KB

    const f16* stf = ws16 + OFF_STF;
    const f16* Wef = ws16 + OFF_WEF;
    const float* be2 = (const float*)(ws16 + OFF_BE2);
    const float* bn2 = be2 + 11520;

    const int t = threadIdx.x, lane = t&63, wid = t>>6;   // wid 0..7
    const int l15 = lane&15, q = lane>>4, qo = q<<3;
    const int rg = wid>>1, cs = wid&1;                 // row-group 0..3, col-half 0..1

    // bijective XCD-chunk swizzle: 640 = 8 * 80
    const int swz = (blockIdx.x & 7)*80 + (blockIdx.x >> 3);
    const int rb  = swz / 10;                          // 128-row group 0..63
    const int i   = swz - rb*10;                       // node 0..9
    const int e0  = 9*i;
    const int rbrow = rb*4 + rg;                       // this wave's 32-row chunk (0..255)

    // ---- prologue: stage edge-0 W into sW0; load ai ----
    {
        const f16* wsrc = Wef + (size_t)e0*16384 + wid*2048 + lane*8;
        f16x8 w0 = *(const f16x8*)(wsrc);
        f16x8 w1 = *(const f16x8*)(wsrc+512);
        f16x8 w2 = *(const f16x8*)(wsrc+1024);
        f16x8 w3 = *(const f16x8*)(wsrc+1536);
        f16* dst = &sW0[wid*2048 + lane*8];
        *(f16x8*)(dst)      = w0;
        *(f16x8*)(dst+512)  = w1;
        *(f16x8*)(dst+1024) = w2;
        *(f16x8*)(dst+1536) = w3;
    }
    f16x8 ai[4];
    {
        const f16* p = stf + ((size_t)i*256 + rbrow)*2048 + lane*8;
        ai[0] = *(const f16x8*)p;        ai[1] = *(const f16x8*)(p+512);
        ai[2] = *(const f16x8*)(p+1024); ai[3] = *(const f16x8*)(p+1536);
    }
    __syncthreads();

    f16* sWc = sW0;                                    // current compute buffer
    f16* sWn = sW1;                                    // staging target

    f32x4 agg[2][4] = {};

    #pragma unroll 1
    for (int e=0; e<8; ++e){
        const int ebase = e0 + e;

        // ---- issue next-edge W staging loads (consumer = ds_write at bottom) ----
        const f16* wsrc = Wef + (size_t)(ebase+1)*16384 + wid*2048 + lane*8;
        f16x8 s0 = *(const f16x8*)(wsrc);
        f16x8 s1 = *(const f16x8*)(wsrc+512);
        f16x8 s2 = *(const f16x8*)(wsrc+1024);
        f16x8 s3 = *(const f16x8*)(wsrc+1536);

        // ---- this edge's A-frags (static-indexed array, loaded fresh) ----
        const int j = e + (e >= i);
        const f16* pj = stf + ((size_t)j*256 + rbrow)*2048 + lane*8;
        f16x8 aj[4];
        aj[0] = *(const f16x8*)pj;        aj[1] = *(const f16x8*)(pj+512);
        aj[2] = *(const f16x8*)(pj+1024); aj[3] = *(const f16x8*)(pj+1536);

        float bv[4];
        #pragma unroll
        for (int c=0; c<4; ++c) bv[c] = be2[ebase*128 + cs*64 + c*16 + l15];

        // ---- compute edge e from sWc ----
        const f16* wb = sWc + cs*2048 + lane*8;
        #pragma unroll
        for (int rt=0; rt<2; ++rt){
            f32x4 msg[4] = {};
            #pragma unroll
            for (int ks4=0; ks4<4; ++ks4){
                f16x8 a = (ks4 < 2) ? ai[rt*2 + ks4] : aj[rt*2 + (ks4-2)];
                #pragma unroll
                for (int c=0; c<4; ++c){
                    f16x8 b = *(const f16x8*)(wb + (ks4*8 + c)*512);
                    msg[c] = MFMA16(a, b, msg[c]);
                }
            }
            // tanh + aggregate: sum tanh = 9 - 2*sum rcp(exp2(S2C*x+b2)+1)
            #pragma unroll
            for (int c=0; c<4; ++c)
                #pragma unroll
                for (int r2=0; r2<4; ++r2){
                    float tt = __builtin_fmaf(msg[c][r2], S2C, bv[c]);
                    float rr = fast_rcp(fast_exp2(tt) + 1.0f);
                    agg[rt][c][r2] = __builtin_fmaf(-2.0f, rr, agg[rt][c][r2]);
                }
        }

        // ---- write staged W into sWn (vmcnt wait lands here, hidden) ----
        {
            f16* dst = sWn + wid*2048 + lane*8;
            *(f16x8*)(dst)      = s0;
            *(f16x8*)(dst+512)  = s1;
            *(f16x8*)(dst+1024) = s2;
            *(f16x8*)(dst+1536) = s3;
        }
        __syncthreads();
        f16* tmp = sWc; sWc = sWn; sWn = tmp;
    }

    // ---- edge 8: compute from sWc; stage W_node into sWn during the body ----
    {
        const f16* wnf = ws16 + OFF_WNF + (size_t)i*14336 + wid*512 + lane*8;
        f16x8 s0 = *(const f16x8*)(wnf);
        f16x8 s1 = *(const f16x8*)(wnf + 4096);
        f16x8 s2 = *(const f16x8*)(wnf + 8192);
        f16x8 s3;
        if (wid < 4) s3 = *(const f16x8*)(wnf + 12288);

        const int ebase = e0 + 8;
        const int j = 8 + (8 >= i);
        const f16* pj = stf + ((size_t)j*256 + rbrow)*2048 + lane*8;
        f16x8 aj[4];
        aj[0] = *(const f16x8*)pj;        aj[1] = *(const f16x8*)(pj+512);
        aj[2] = *(const f16x8*)(pj+1024); aj[3] = *(const f16x8*)(pj+1536);

        float bv[4];
        #pragma unroll
        for (int c=0; c<4; ++c) bv[c] = be2[ebase*128 + cs*64 + c*16 + l15];

        const f16* wb = sWc + cs*2048 + lane*8;
        #pragma unroll
        for (int rt=0; rt<2; ++rt){
            f32x4 msg[4] = {};
            #pragma unroll
            for (int ks4=0; ks4<4; ++ks4){
                f16x8 a = (ks4 < 2) ? ai[rt*2 + ks4] : aj[rt*2 + (ks4-2)];
                #pragma unroll
                for (int c=0; c<4; ++c){
                    f16x8 b = *(const f16x8*)(wb + (ks4*8 + c)*512);
                    msg[c] = MFMA16(a, b, msg[c]);
                }
            }
            #pragma unroll
            for (int c=0; c<4; ++c)
                #pragma unroll
                for (int r2=0; r2<4; ++r2){
                    float tt = __builtin_fmaf(msg[c][r2], S2C, bv[c]);
                    float rr = fast_rcp(fast_exp2(tt) + 1.0f);
                    agg[rt][c][r2] = __builtin_fmaf(-2.0f, rr, agg[rt][c][r2]);
                }
        }

        // W_node frags -> sWn
        f16* dst = sWn + wid*512 + lane*8;
        *(f16x8*)(dst)        = s0;
        *(f16x8*)(dst + 4096) = s1;
        *(f16x8*)(dst + 8192) = s2;
        if (wid < 4) *(f16x8*)(dst + 12288) = s3;
    }
    __syncthreads();   // all waves done reading sWc (W8) -> safe to overwrite with sAgg

    // ---- agg (C-layout) -> sAgg f16 in sWc (A-layout, swizzled), +9 fold ----
    #pragma unroll
    for (int rt=0; rt<2; ++rt)
        #pragma unroll
        for (int c=0; c<4; ++c)
            #pragma unroll
            for (int r2=0; r2<4; ++r2){
                int lrow = rg*32 + rt*16 + q*4 + r2;   // 0..127
                int col  = cs*64 + c*16 + l15;         // 0..127
                sWc[lrow*128 + (((col>>3) ^ (lrow&7))<<3) + (col&7)] = (f16)(agg[rt][c][r2] + 9.0f);
            }
    __syncthreads();

    // ---- stage 2: out = tanh([agg|states|action] @ Wn_perm[i] + bn) ; wave = 16 rows ----
    f32x4 acc[4] = {};
    const f16* acp = ws16 + OFF_AC;
    const f16* zb  = ws16 + OFF_Z;
    const int b0 = rb*128;
    #pragma unroll
    for (int ks2=0; ks2<7; ++ks2){
        f16x8 a;
        if (ks2 < 4){                                  // agg region (K 0..127) from LDS
            int lrow = wid*16 + l15;
            a = *(const f16x8*)(sWc + lrow*128 + (((ks2*4 + q) ^ (l15&7))<<3));
        } else if (ks2 < 6){                           // states region (K 128..191)
            a = *(const f16x8*)(stf + ((size_t)i*256 + rb*4 + (wid>>1))*2048
                                + (wid&1)*1024 + (ks2-4)*512 + lane*8);
        } else {                                       // action (K 192..207) + zero pad
            int row = b0 + wid*16 + l15;
            const f16* ap = (q < 2) ? (acp + ((size_t)row*10 + i)*16 + qo) : zb;
            a = *(const f16x8*)ap;
        }
        #pragma unroll
        for (int c=0; c<4; ++c){
            f16x8 bf = *(const f16x8*)(sWn + (ks2*4+c)*512 + lane*8);
            acc[c] = MFMA16(a, bf, acc[c]);
        }
    }
    float bnv[4];
    #pragma unroll
    for (int c=0; c<4; ++c) bnv[c] = bn2[i*64 + c*16 + l15];
    #pragma unroll
    for (int c=0; c<4; ++c)
        #pragma unroll
        for (int r2=0; r2<4; ++r2){
            int row = b0 + wid*16 + q*4 + r2;
            int col = c*16 + l15;
            float tt = __builtin_fmaf(acc[c][r2], S2C, bnv[c]);
            float rr = fast_rcp(fast_exp2(tt) + 1.0f);
            out[((size_t)row*10 + i)*64 + col] = __builtin_fmaf(-2.0f, rr, 1.0f);
        }
}

extern "C" void kernel_launch(void* const* d_in, const int* in_sizes, int n_in,
                              void* d_out, int out_size, void* d_ws, size_t ws_size,
                              hipStream_t stream) {
    const float* states = (const float*)d_in[0];
    const float* action = (const float*)d_in[1];
    const float* W_edge = (const float*)d_in[2];
    const float* b_edge = (const float*)d_in[3];
    const float* W_node = (const float*)d_in[4];
    const float* b_node = (const float*)d_in[5];
    f16* ws16 = (f16*)d_ws;   // ~16.4 MB used

    hipLaunchKernelGGL(prep, dim3(4678), dim3(256), 0, stream,
                       states, action, W_edge, b_edge, W_node, b_node, ws16);
    hipLaunchKernelGGL(gnn_main, dim3(640), dim3(512), 0, stream,
                       ws16, (float*)d_out);
}